// Round 1
// baseline (677.544 us; speedup 1.0000x reference)
//
#include <hip/hip_runtime.h>

#define S0V 25
#define S1V 10
#define NBATCH 4096
#define FDIM 128
#define L1N (NBATCH * 11)   // 45056 level-1 nodes

typedef __attribute__((ext_vector_type(8))) short short8;
typedef __attribute__((ext_vector_type(4))) float f32x4;

__device__ __forceinline__ ushort f2bf(float f) {
  unsigned int x = __builtin_bit_cast(unsigned int, f);
  x += 0x7fffu + ((x >> 16) & 1u);   // round-to-nearest-even
  return (ushort)(x >> 16);
}
__device__ __forceinline__ float bf2f(ushort u) {
  unsigned int x = ((unsigned int)u) << 16;
  return __builtin_bit_cast(float, x);
}

// ---------------------------------------------------------------------------
// Kernel 1: per level-1 node (b,j): X[i] = [ feat[self] ; mean_s feat[nbr0] ]
// One wave per node; lane handles 2 consecutive floats (8B coalesced loads).
// ---------------------------------------------------------------------------
__global__ __launch_bounds__(256) void gather_mean_kernel(
    const float* __restrict__ feat, const int* __restrict__ nodes,
    const int* __restrict__ nbr1, const int* __restrict__ nbr0,
    ushort* __restrict__ Xb) {
  const int wave = threadIdx.x >> 6;
  const int lane = threadIdx.x & 63;
  const int i = blockIdx.x * 4 + wave;          // grid covers exactly 45056
  const int b = i / 11;
  const int j = i - b * 11;
  const int self = (j == 0) ? nodes[b] : nbr1[b * S1V + (j - 1)];
  const int* nb = nbr0 + (size_t)i * S0V;
  float ax = 0.f, ay = 0.f;
#pragma unroll
  for (int s = 0; s < S0V; ++s) {
    const int rr = nb[s];
    const float2 v = *(const float2*)(feat + (size_t)rr * FDIM + lane * 2);
    ax += v.x; ay += v.y;
  }
  const float2 sv = *(const float2*)(feat + (size_t)self * FDIM + lane * 2);
  ushort* out = Xb + (size_t)i * 256;
  ushort2 a, m;
  a.x = f2bf(sv.x); a.y = f2bf(sv.y);
  m.x = f2bf(ax * (1.f / 25.f)); m.y = f2bf(ay * (1.f / 25.f));
  *(ushort2*)(out + lane * 2) = a;
  *(ushort2*)(out + 128 + lane * 2) = m;
}

// ---------------------------------------------------------------------------
// Kernel 2/3b: out = l2norm(relu(A[M,256](bf16) @ W[128,256]^T(f32) + bias))
// BM=128, BN=128 (full), BK=64. 256 threads = 4 waves, wave owns 32 rows
// (full 128-col rows -> l2norm reduction stays in-wave/in-quad).
// mfma_f32_16x16x32_bf16; A frag: A[m=lane&15][k=(lane>>4)*8+j],
// B frag (B^T, row-major [n][k]): same indexing; C: col=lane&15,
// row=(lane>>4)*4+reg  (m89/m91-verified layouts).
// ---------------------------------------------------------------------------
template <int OUT_BF16>
__global__ __launch_bounds__(256) void gemm_relu_l2norm_kernel(
    const ushort* __restrict__ A, const float* __restrict__ W,
    const float* __restrict__ bias, void* __restrict__ outp, int M) {
  __shared__ ushort At[128 * 80];   // row stride 80 ushort = 160 B (16B aligned)
  __shared__ ushort Bt[128 * 80];
  const int tid = threadIdx.x;
  const int m0 = blockIdx.x * 128;
  const int wave = tid >> 6;
  const int lane = tid & 63;
  const int q = lane >> 4;
  const int r = lane & 15;
  const int wm0 = wave * 32;

  f32x4 acc[2][8] = {};

#pragma unroll
  for (int kt = 0; kt < 4; ++kt) {
    const int k0 = kt * 64;
    // stage A slice: 128 rows x 64 cols bf16 = 1024 chunks of 16B
#pragma unroll
    for (int c = 0; c < 4; ++c) {
      const int idx = tid + c * 256;
      const int row = idx >> 3, cc = idx & 7;
      const short8 v =
          *(const short8*)(A + (size_t)(m0 + row) * 256 + k0 + cc * 8);
      *(short8*)(At + row * 80 + cc * 8) = v;
    }
    // stage B slice: W fp32 -> bf16, 128 rows x 64 cols = 2048 float4 chunks
#pragma unroll
    for (int c = 0; c < 8; ++c) {
      const int idx = tid + c * 256;
      const int row = idx >> 4, cc = idx & 15;
      const float4 v = *(const float4*)(W + row * 256 + k0 + cc * 4);
      ushort4 h;
      h.x = f2bf(v.x); h.y = f2bf(v.y); h.z = f2bf(v.z); h.w = f2bf(v.w);
      *(ushort4*)(Bt + row * 80 + cc * 4) = h;
    }
    __syncthreads();
#pragma unroll
    for (int kk = 0; kk < 2; ++kk) {
      const int koff = kk * 32 + q * 8;
      const short8 a0 = *(const short8*)(At + (wm0 + r) * 80 + koff);
      const short8 a1 = *(const short8*)(At + (wm0 + 16 + r) * 80 + koff);
#pragma unroll
      for (int nf = 0; nf < 8; ++nf) {
        const short8 bb = *(const short8*)(Bt + (nf * 16 + r) * 80 + koff);
        acc[0][nf] = __builtin_amdgcn_mfma_f32_16x16x32_bf16(a0, bb, acc[0][nf], 0, 0, 0);
        acc[1][nf] = __builtin_amdgcn_mfma_f32_16x16x32_bf16(a1, bb, acc[1][nf], 0, 0, 0);
      }
    }
    __syncthreads();
  }

  // epilogue: bias + relu + per-row l2 normalize + store
  float bvals[8];
#pragma unroll
  for (int nf = 0; nf < 8; ++nf) bvals[nf] = bias[nf * 16 + r];

  float ss[2][4] = {};
#pragma unroll
  for (int mf = 0; mf < 2; ++mf)
#pragma unroll
    for (int nf = 0; nf < 8; ++nf)
#pragma unroll
      for (int reg = 0; reg < 4; ++reg) {
        float v = acc[mf][nf][reg] + bvals[nf];
        v = fmaxf(v, 0.f);
        acc[mf][nf][reg] = v;
        ss[mf][reg] += v * v;
      }
  // reduce sum-of-squares across the 16 lanes of each quad (same row group)
#pragma unroll
  for (int off = 1; off < 16; off <<= 1)
#pragma unroll
    for (int mf = 0; mf < 2; ++mf)
#pragma unroll
      for (int reg = 0; reg < 4; ++reg)
        ss[mf][reg] += __shfl_xor(ss[mf][reg], off, 16);

  float inv[2][4];
#pragma unroll
  for (int mf = 0; mf < 2; ++mf)
#pragma unroll
    for (int reg = 0; reg < 4; ++reg)
      inv[mf][reg] = 1.f / fmaxf(sqrtf(ss[mf][reg]), 1e-12f);

#pragma unroll
  for (int mf = 0; mf < 2; ++mf)
#pragma unroll
    for (int reg = 0; reg < 4; ++reg) {
      const int row = m0 + wm0 + mf * 16 + q * 4 + reg;
#pragma unroll
      for (int nf = 0; nf < 8; ++nf) {
        const int col = nf * 16 + r;
        const float v = acc[mf][nf][reg] * inv[mf][reg];
        if (OUT_BF16) {
          ((ushort*)outp)[(size_t)row * 128 + col] = f2bf(v);
        } else {
          ((float*)outp)[(size_t)row * 128 + col] = v;
        }
      }
    }
}

// ---------------------------------------------------------------------------
// Kernel 3a: X2[b] = [ H1[b,0,:] ; mean_{j=1..10} H1[b,j,:] ]  (bf16)
// One wave per target b; lane handles 2 cols.
// ---------------------------------------------------------------------------
__global__ __launch_bounds__(256) void build_x2_kernel(
    const ushort* __restrict__ H1, ushort* __restrict__ X2) {
  const int wave = threadIdx.x >> 6;
  const int lane = threadIdx.x & 63;
  const int b = blockIdx.x * 4 + wave;          // grid covers exactly 4096
  const ushort* base = H1 + (size_t)b * 11 * 128;
  const ushort2 s = *(const ushort2*)(base + lane * 2);
  float ax = 0.f, ay = 0.f;
#pragma unroll
  for (int j = 1; j <= 10; ++j) {
    const ushort2 v = *(const ushort2*)(base + j * 128 + lane * 2);
    ax += bf2f(v.x); ay += bf2f(v.y);
  }
  ushort* out = X2 + (size_t)b * 256;
  ushort2 m;
  m.x = f2bf(ax * 0.1f); m.y = f2bf(ay * 0.1f);
  *(ushort2*)(out + lane * 2) = s;
  *(ushort2*)(out + 128 + lane * 2) = m;
}

extern "C" void kernel_launch(void* const* d_in, const int* in_sizes, int n_in,
                              void* d_out, int out_size, void* d_ws, size_t ws_size,
                              hipStream_t stream) {
  const float* feat  = (const float*)d_in[0];   // [1e6,128]
  const float* W0    = (const float*)d_in[1];   // [128,256]
  const float* b0    = (const float*)d_in[2];   // [128]
  const float* W1    = (const float*)d_in[3];   // [128,256]
  const float* b1    = (const float*)d_in[4];   // [128]
  const int* nodes   = (const int*)d_in[5];     // [4096]
  const int* nbr1    = (const int*)d_in[6];     // [4096,10]
  const int* nbr0    = (const int*)d_in[7];     // [4096,11,25]
  float* out = (float*)d_out;                   // [4096,128] f32

  // workspace layout (all 16B aligned)
  ushort* Xb = (ushort*)d_ws;                                   // 45056*256*2 = 23,068,672 B
  ushort* H1 = (ushort*)((char*)d_ws + 23068672);               // 45056*128*2 = 11,534,336 B
  ushort* X2 = (ushort*)((char*)d_ws + 23068672 + 11534336);    //  4096*256*2 =  2,097,152 B

  // K1: gather + neighbor mean -> Xb [45056,256] bf16
  gather_mean_kernel<<<L1N / 4, 256, 0, stream>>>(feat, nodes, nbr1, nbr0, Xb);
  // K2: H1 = l2norm(relu(Xb @ W0^T + b0)) -> bf16 [45056,128]
  gemm_relu_l2norm_kernel<1><<<L1N / 128, 256, 0, stream>>>(Xb, W0, b0, (void*)H1, L1N);
  // K3a: X2 = [h1_self ; mean(h1_nbrs)] -> bf16 [4096,256]
  build_x2_kernel<<<NBATCH / 4, 256, 0, stream>>>(H1, X2);
  // K3b: z = l2norm(relu(X2 @ W1^T + b1)) -> f32 d_out [4096,128]
  gemm_relu_l2norm_kernel<0><<<NBATCH / 128, 256, 0, stream>>>(X2, W1, b1, (void*)out, NBATCH);
}

// Round 2
// 677.434 us; speedup vs baseline: 1.0002x; 1.0002x over previous
//
#include <hip/hip_runtime.h>

#define S0V 25
#define S1V 10
#define NBATCH 4096
#define FDIM 128
#define L1N (NBATCH * 11)   // 45056 level-1 nodes

typedef __attribute__((ext_vector_type(8))) short short8;
typedef __attribute__((ext_vector_type(4))) float f32x4;

__device__ __forceinline__ ushort f2bf(float f) {
  unsigned int x = __builtin_bit_cast(unsigned int, f);
  x += 0x7fffu + ((x >> 16) & 1u);   // round-to-nearest-even
  return (ushort)(x >> 16);
}
__device__ __forceinline__ float bf2f(ushort u) {
  unsigned int x = ((unsigned int)u) << 16;
  return __builtin_bit_cast(float, x);
}

// ---------------------------------------------------------------------------
// Kernel 1 (v2): per level-1 node (b,j): X[i] = [ feat[self] ; mean_s feat[nbr0] ]
// One wave per node. Wave is split into two 32-lane halves; each float4 load
// covers TWO neighbor rows (even s in lanes 0-31, odd s in lanes 32-63) at
// 16 B/lane. All 25 neighbor indices come from ONE lane-parallel load,
// distributed with __shfl. Per node: 14 dwordx4 loads + 1 idx load + 2 stores.
// ---------------------------------------------------------------------------
__global__ __launch_bounds__(256) void gather_mean_kernel(
    const float* __restrict__ feat, const int* __restrict__ nodes,
    const int* __restrict__ nbr1, const int* __restrict__ nbr0,
    ushort* __restrict__ Xb) {
  const int wave = threadIdx.x >> 6;
  const int lane = threadIdx.x & 63;
  const int half = lane >> 5;        // 0: even s, 1: odd s
  const int l = lane & 31;           // column group (4 floats per lane)
  const int i = blockIdx.x * 4 + wave;  // grid covers exactly 45056
  const int b = i / 11;
  const int j = i - b * 11;
  const int self = (j == 0) ? nodes[b] : nbr1[b * S1V + (j - 1)];
  const int* nb = nbr0 + (size_t)i * S0V;

  // one lane-parallel index load for all 25 neighbors
  const int myidx = nb[(lane < S0V) ? lane : 0];

  float4 acc = make_float4(0.f, 0.f, 0.f, 0.f);
#pragma unroll
  for (int k = 0; k < 12; ++k) {
    const int rr = __shfl(myidx, 2 * k + half);
    const float4 v = *(const float4*)(feat + (size_t)rr * FDIM + l * 4);
    acc.x += v.x; acc.y += v.y; acc.z += v.z; acc.w += v.w;
  }
  {  // s = 24: both halves load the same row, only half 0 accumulates
    const int rr = __shfl(myidx, 24);
    const float4 v = *(const float4*)(feat + (size_t)rr * FDIM + l * 4);
    if (half == 0) { acc.x += v.x; acc.y += v.y; acc.z += v.z; acc.w += v.w; }
  }
  // combine the two halves: lane l pairs with lane l^32 (same columns)
  acc.x += __shfl_xor(acc.x, 32);
  acc.y += __shfl_xor(acc.y, 32);
  acc.z += __shfl_xor(acc.z, 32);
  acc.w += __shfl_xor(acc.w, 32);

  // self row (both halves read the same 512 B row; half 0 stores it)
  const float4 sv = *(const float4*)(feat + (size_t)self * FDIM + l * 4);

  float4 val;
  if (half == 0) {
    val = sv;
  } else {
    val.x = acc.x * (1.f / 25.f); val.y = acc.y * (1.f / 25.f);
    val.z = acc.z * (1.f / 25.f); val.w = acc.w * (1.f / 25.f);
  }
  ushort4 h;
  h.x = f2bf(val.x); h.y = f2bf(val.y); h.z = f2bf(val.z); h.w = f2bf(val.w);
  // half 0 -> cols [0,128) (self); half 1 -> cols [128,256) (mean)
  *(ushort4*)(Xb + (size_t)i * 256 + half * 128 + l * 4) = h;
}

// ---------------------------------------------------------------------------
// Kernel 2/3b: out = l2norm(relu(A[M,256](bf16) @ W[128,256]^T(f32) + bias))
// BM=128, BN=128 (full), BK=64. 256 threads = 4 waves, wave owns 32 rows.
// mfma_f32_16x16x32_bf16; A frag: A[m=lane&15][k=(lane>>4)*8+j],
// B frag (B^T, row-major [n][k]): same indexing; C: col=lane&15,
// row=(lane>>4)*4+reg  (m89/m91-verified layouts).
// ---------------------------------------------------------------------------
template <int OUT_BF16>
__global__ __launch_bounds__(256) void gemm_relu_l2norm_kernel(
    const ushort* __restrict__ A, const float* __restrict__ W,
    const float* __restrict__ bias, void* __restrict__ outp, int M) {
  __shared__ ushort At[128 * 80];   // row stride 80 ushort = 160 B (16B aligned)
  __shared__ ushort Bt[128 * 80];
  const int tid = threadIdx.x;
  const int m0 = blockIdx.x * 128;
  const int wave = tid >> 6;
  const int lane = tid & 63;
  const int q = lane >> 4;
  const int r = lane & 15;
  const int wm0 = wave * 32;

  f32x4 acc[2][8] = {};

#pragma unroll
  for (int kt = 0; kt < 4; ++kt) {
    const int k0 = kt * 64;
    // stage A slice: 128 rows x 64 cols bf16 = 1024 chunks of 16B
#pragma unroll
    for (int c = 0; c < 4; ++c) {
      const int idx = tid + c * 256;
      const int row = idx >> 3, cc = idx & 7;
      const short8 v =
          *(const short8*)(A + (size_t)(m0 + row) * 256 + k0 + cc * 8);
      *(short8*)(At + row * 80 + cc * 8) = v;
    }
    // stage B slice: W fp32 -> bf16, 128 rows x 64 cols = 2048 float4 chunks
#pragma unroll
    for (int c = 0; c < 8; ++c) {
      const int idx = tid + c * 256;
      const int row = idx >> 4, cc = idx & 15;
      const float4 v = *(const float4*)(W + row * 256 + k0 + cc * 4);
      ushort4 h;
      h.x = f2bf(v.x); h.y = f2bf(v.y); h.z = f2bf(v.z); h.w = f2bf(v.w);
      *(ushort4*)(Bt + row * 80 + cc * 4) = h;
    }
    __syncthreads();
#pragma unroll
    for (int kk = 0; kk < 2; ++kk) {
      const int koff = kk * 32 + q * 8;
      const short8 a0 = *(const short8*)(At + (wm0 + r) * 80 + koff);
      const short8 a1 = *(const short8*)(At + (wm0 + 16 + r) * 80 + koff);
#pragma unroll
      for (int nf = 0; nf < 8; ++nf) {
        const short8 bb = *(const short8*)(Bt + (nf * 16 + r) * 80 + koff);
        acc[0][nf] = __builtin_amdgcn_mfma_f32_16x16x32_bf16(a0, bb, acc[0][nf], 0, 0, 0);
        acc[1][nf] = __builtin_amdgcn_mfma_f32_16x16x32_bf16(a1, bb, acc[1][nf], 0, 0, 0);
      }
    }
    __syncthreads();
  }

  // epilogue: bias + relu + per-row l2 normalize + store
  float bvals[8];
#pragma unroll
  for (int nf = 0; nf < 8; ++nf) bvals[nf] = bias[nf * 16 + r];

  float ss[2][4] = {};
#pragma unroll
  for (int mf = 0; mf < 2; ++mf)
#pragma unroll
    for (int nf = 0; nf < 8; ++nf)
#pragma unroll
      for (int reg = 0; reg < 4; ++reg) {
        float v = acc[mf][nf][reg] + bvals[nf];
        v = fmaxf(v, 0.f);
        acc[mf][nf][reg] = v;
        ss[mf][reg] += v * v;
      }
  // reduce sum-of-squares across the 16 lanes of each quad (same row group)
#pragma unroll
  for (int off = 1; off < 16; off <<= 1)
#pragma unroll
    for (int mf = 0; mf < 2; ++mf)
#pragma unroll
      for (int reg = 0; reg < 4; ++reg)
        ss[mf][reg] += __shfl_xor(ss[mf][reg], off, 16);

  float inv[2][4];
#pragma unroll
  for (int mf = 0; mf < 2; ++mf)
#pragma unroll
    for (int reg = 0; reg < 4; ++reg)
      inv[mf][reg] = 1.f / fmaxf(sqrtf(ss[mf][reg]), 1e-12f);

#pragma unroll
  for (int mf = 0; mf < 2; ++mf)
#pragma unroll
    for (int reg = 0; reg < 4; ++reg) {
      const int row = m0 + wm0 + mf * 16 + q * 4 + reg;
#pragma unroll
      for (int nf = 0; nf < 8; ++nf) {
        const int col = nf * 16 + r;
        const float v = acc[mf][nf][reg] * inv[mf][reg];
        if (OUT_BF16) {
          ((ushort*)outp)[(size_t)row * 128 + col] = f2bf(v);
        } else {
          ((float*)outp)[(size_t)row * 128 + col] = v;
        }
      }
    }
}

// ---------------------------------------------------------------------------
// Kernel 3a: X2[b] = [ H1[b,0,:] ; mean_{j=1..10} H1[b,j,:] ]  (bf16)
// One wave per target b; lane handles 2 cols.
// ---------------------------------------------------------------------------
__global__ __launch_bounds__(256) void build_x2_kernel(
    const ushort* __restrict__ H1, ushort* __restrict__ X2) {
  const int wave = threadIdx.x >> 6;
  const int lane = threadIdx.x & 63;
  const int b = blockIdx.x * 4 + wave;          // grid covers exactly 4096
  const ushort* base = H1 + (size_t)b * 11 * 128;
  const ushort2 s = *(const ushort2*)(base + lane * 2);
  float ax = 0.f, ay = 0.f;
#pragma unroll
  for (int j = 1; j <= 10; ++j) {
    const ushort2 v = *(const ushort2*)(base + j * 128 + lane * 2);
    ax += bf2f(v.x); ay += bf2f(v.y);
  }
  ushort* out = X2 + (size_t)b * 256;
  ushort2 m;
  m.x = f2bf(ax * 0.1f); m.y = f2bf(ay * 0.1f);
  *(ushort2*)(out + lane * 2) = s;
  *(ushort2*)(out + 128 + lane * 2) = m;
}

extern "C" void kernel_launch(void* const* d_in, const int* in_sizes, int n_in,
                              void* d_out, int out_size, void* d_ws, size_t ws_size,
                              hipStream_t stream) {
  const float* feat  = (const float*)d_in[0];   // [1e6,128]
  const float* W0    = (const float*)d_in[1];   // [128,256]
  const float* b0    = (const float*)d_in[2];   // [128]
  const float* W1    = (const float*)d_in[3];   // [128,256]
  const float* b1    = (const float*)d_in[4];   // [128]
  const int* nodes   = (const int*)d_in[5];     // [4096]
  const int* nbr1    = (const int*)d_in[6];     // [4096,10]
  const int* nbr0    = (const int*)d_in[7];     // [4096,11,25]
  float* out = (float*)d_out;                   // [4096,128] f32

  // workspace layout (all 16B aligned)
  ushort* Xb = (ushort*)d_ws;                                   // 45056*256*2 = 23,068,672 B
  ushort* H1 = (ushort*)((char*)d_ws + 23068672);               // 45056*128*2 = 11,534,336 B
  ushort* X2 = (ushort*)((char*)d_ws + 23068672 + 11534336);    //  4096*256*2 =  2,097,152 B

  // K1: gather + neighbor mean -> Xb [45056,256] bf16
  gather_mean_kernel<<<L1N / 4, 256, 0, stream>>>(feat, nodes, nbr1, nbr0, Xb);
  // K2: H1 = l2norm(relu(Xb @ W0^T + b0)) -> bf16 [45056,128]
  gemm_relu_l2norm_kernel<1><<<L1N / 128, 256, 0, stream>>>(Xb, W0, b0, (void*)H1, L1N);
  // K3a: X2 = [h1_self ; mean(h1_nbrs)] -> bf16 [4096,256]
  build_x2_kernel<<<NBATCH / 4, 256, 0, stream>>>(H1, X2);
  // K3b: z = l2norm(relu(X2 @ W1^T + b1)) -> f32 d_out [4096,128]
  gemm_relu_l2norm_kernel<0><<<NBATCH / 128, 256, 0, stream>>>(X2, W1, b1, (void*)out, NBATCH);
}

// Round 3
// 670.058 us; speedup vs baseline: 1.0112x; 1.0110x over previous
//
#include <hip/hip_runtime.h>

#define S0V 25
#define S1V 10
#define NBATCH 4096
#define FDIM 128
#define L1N (NBATCH * 11)   // 45056 level-1 nodes

typedef __attribute__((ext_vector_type(8))) short short8;
typedef __attribute__((ext_vector_type(4))) float f32x4;

__device__ __forceinline__ ushort f2bf(float f) {
  unsigned int x = __builtin_bit_cast(unsigned int, f);
  x += 0x7fffu + ((x >> 16) & 1u);   // round-to-nearest-even
  return (ushort)(x >> 16);
}
__device__ __forceinline__ float bf2f(ushort u) {
  unsigned int x = ((unsigned int)u) << 16;
  return __builtin_bit_cast(float, x);
}

// ---------------------------------------------------------------------------
// Prep: convert W0,W1 (fp32 [128,256]) to bf16 once. 64 blocks x 256 thr.
// ---------------------------------------------------------------------------
__global__ __launch_bounds__(256) void prep_w_kernel(
    const float* __restrict__ W0, const float* __restrict__ W1,
    ushort* __restrict__ Wb0, ushort* __restrict__ Wb1) {
  const int idx = blockIdx.x * 256 + threadIdx.x;   // 16384 threads, 4 elems each
  const int sel = idx >> 13;                        // 0: W0, 1: W1 (8192 float4 each)
  const int k = idx & 8191;
  const float4 v = sel ? ((const float4*)W1)[k] : ((const float4*)W0)[k];
  ushort4 h;
  h.x = f2bf(v.x); h.y = f2bf(v.y); h.z = f2bf(v.z); h.w = f2bf(v.w);
  if (sel) ((ushort4*)Wb1)[k] = h; else ((ushort4*)Wb0)[k] = h;
}

// ---------------------------------------------------------------------------
// Shared GEMM+epilogue: out_rows = l2norm(relu(Xs[64,256] @ Wb[128,256]^T + b))
// 512 threads = 8 waves. Wave w: m-frag = w&3 (16 rows), col-half = w>>2
// (64 cols = 4 n-frags). K staged from global bf16 W in 64-col chunks.
// mfma_f32_16x16x32_bf16 layouts (m89/m91-verified): A[m=lane&15][k=q*8+j],
// B^T row-major same; C: col=lane&15, row=q*4+reg.
// Row sum-of-squares crosses the two col-half waves -> combined via ssb LDS.
// ---------------------------------------------------------------------------
template <int OUT_BF16>
__device__ __forceinline__ void gemm_norm_64(
    ushort* __restrict__ Xs,   // [64][264] bf16 LDS
    ushort* __restrict__ Wt,   // [128][72] bf16 LDS staging
    float* __restrict__ ssb,   // [64][2] LDS
    const ushort* __restrict__ Wb, const float* __restrict__ bias,
    void* __restrict__ outp, int row0) {
  const int tid = threadIdx.x;
  const int wave = tid >> 6, lane = tid & 63;
  const int q = lane >> 4, r = lane & 15;
  const int mf = wave & 3, ch = wave >> 2;

  f32x4 acc[4] = {};
#pragma unroll
  for (int kt = 0; kt < 4; ++kt) {
    // stage W chunk: 128 rows x 64 cols bf16 = 1024 short8; 512 thr x 2
#pragma unroll
    for (int p = 0; p < 2; ++p) {
      const int idx = tid + p * 512;
      const int row = idx >> 3, cc = idx & 7;
      const short8 v = *(const short8*)(Wb + row * 256 + kt * 64 + cc * 8);
      *(short8*)(Wt + row * 72 + cc * 8) = v;
    }
    __syncthreads();
#pragma unroll
    for (int kk = 0; kk < 2; ++kk) {
      const int koff = kk * 32 + q * 8;
      const short8 a = *(const short8*)(Xs + (mf * 16 + r) * 264 + kt * 64 + koff);
#pragma unroll
      for (int nf = 0; nf < 4; ++nf) {
        const short8 bb = *(const short8*)(Wt + (ch * 64 + nf * 16 + r) * 72 + koff);
        acc[nf] = __builtin_amdgcn_mfma_f32_16x16x32_bf16(a, bb, acc[nf], 0, 0, 0);
      }
    }
    __syncthreads();
  }

  float bv[4];
#pragma unroll
  for (int nf = 0; nf < 4; ++nf) bv[nf] = bias[ch * 64 + nf * 16 + r];

  float ss[4] = {0.f, 0.f, 0.f, 0.f};
#pragma unroll
  for (int nf = 0; nf < 4; ++nf)
#pragma unroll
    for (int reg = 0; reg < 4; ++reg) {
      float v = acc[nf][reg] + bv[nf];
      v = fmaxf(v, 0.f);
      acc[nf][reg] = v;
      ss[reg] += v * v;
    }
  // reduce over the 16 lanes of the quad (cols within this half)
#pragma unroll
  for (int off = 1; off < 16; off <<= 1)
#pragma unroll
    for (int reg = 0; reg < 4; ++reg) ss[reg] += __shfl_xor(ss[reg], off, 16);
  // combine the two col-halves through LDS
  if (r == 0) {
#pragma unroll
    for (int reg = 0; reg < 4; ++reg)
      ssb[(mf * 16 + q * 4 + reg) * 2 + ch] = ss[reg];
  }
  __syncthreads();
#pragma unroll
  for (int reg = 0; reg < 4; ++reg) {
    const int lrow = mf * 16 + q * 4 + reg;
    const float tot = ssb[lrow * 2] + ssb[lrow * 2 + 1];
    const float inv = 1.f / fmaxf(sqrtf(tot), 1e-12f);
#pragma unroll
    for (int nf = 0; nf < 4; ++nf) {
      const int col = ch * 64 + nf * 16 + r;
      const float v = acc[nf][reg] * inv;
      if (OUT_BF16)
        ((ushort*)outp)[(size_t)(row0 + lrow) * 128 + col] = f2bf(v);
      else
        ((float*)outp)[(size_t)(row0 + lrow) * 128 + col] = v;
    }
  }
}

// ---------------------------------------------------------------------------
// Fused layer 1: gather+mean -> LDS X tile (skips global Xb) -> GEMM W0
// -> relu -> l2norm -> H1 (bf16). 64 nodes/block, 512 threads, grid 704.
// Gather: wave split into two 32-lane halves loading two neighbor rows per
// float4 instruction; all 25 indices from one lane-parallel load + __shfl.
// LDS 52.7 KB -> 2 blocks/CU at __launch_bounds__(512,4).
// ---------------------------------------------------------------------------
__global__ __launch_bounds__(512, 4) void fused_l1_kernel(
    const float* __restrict__ feat, const int* __restrict__ nodes,
    const int* __restrict__ nbr1, const int* __restrict__ nbr0,
    const ushort* __restrict__ Wb0, const float* __restrict__ b0,
    ushort* __restrict__ H1) {
  __shared__ ushort Xs[64 * 264];
  __shared__ ushort Wt[128 * 72];
  __shared__ float ssb[128];
  const int tid = threadIdx.x;
  const int wave = tid >> 6, lane = tid & 63;
  const int half = lane >> 5, l = lane & 31;
  const int i0 = blockIdx.x * 64;

  for (int t = 0; t < 8; ++t) {
    const int row = wave * 8 + t;
    const int i = i0 + row;
    const int b = i / 11;
    const int j = i - b * 11;
    const int self = (j == 0) ? nodes[b] : nbr1[b * S1V + (j - 1)];
    const int myidx = nbr0[(size_t)i * S0V + ((lane < S0V) ? lane : 0)];

    float4 acc = make_float4(0.f, 0.f, 0.f, 0.f);
#pragma unroll
    for (int k = 0; k < 12; ++k) {
      const int rr = __shfl(myidx, 2 * k + half);
      const float4 v = *(const float4*)(feat + (size_t)rr * FDIM + l * 4);
      acc.x += v.x; acc.y += v.y; acc.z += v.z; acc.w += v.w;
    }
    {  // s = 24: both halves load the same row, only half 0 accumulates
      const int rr = __shfl(myidx, 24);
      const float4 v = *(const float4*)(feat + (size_t)rr * FDIM + l * 4);
      if (half == 0) { acc.x += v.x; acc.y += v.y; acc.z += v.z; acc.w += v.w; }
    }
    acc.x += __shfl_xor(acc.x, 32);
    acc.y += __shfl_xor(acc.y, 32);
    acc.z += __shfl_xor(acc.z, 32);
    acc.w += __shfl_xor(acc.w, 32);

    const float4 sv = *(const float4*)(feat + (size_t)self * FDIM + l * 4);
    float4 val;
    if (half == 0) {
      val = sv;
    } else {
      val.x = acc.x * (1.f / 25.f); val.y = acc.y * (1.f / 25.f);
      val.z = acc.z * (1.f / 25.f); val.w = acc.w * (1.f / 25.f);
    }
    ushort4 h;
    h.x = f2bf(val.x); h.y = f2bf(val.y); h.z = f2bf(val.z); h.w = f2bf(val.w);
    *(ushort4*)(Xs + row * 264 + half * 128 + l * 4) = h;
  }
  __syncthreads();
  gemm_norm_64<1>(Xs, Wt, ssb, Wb0, b0, (void*)H1, i0);
}

// ---------------------------------------------------------------------------
// Fused layer 2: build X2 tile [self ; mean(10 nbr reps)] in LDS from H1,
// then GEMM W1 -> relu -> l2norm -> d_out (f32). 64 targets/block, grid 64.
// ---------------------------------------------------------------------------
__global__ __launch_bounds__(512, 4) void fused_l2_kernel(
    const ushort* __restrict__ H1, const ushort* __restrict__ Wb1,
    const float* __restrict__ b1, float* __restrict__ out) {
  __shared__ ushort Xs[64 * 264];
  __shared__ ushort Wt[128 * 72];
  __shared__ float ssb[128];
  const int tid = threadIdx.x;
  const int wave = tid >> 6, lane = tid & 63;
  const int t0 = blockIdx.x * 64;

  for (int t = 0; t < 8; ++t) {
    const int row = wave * 8 + t;
    const ushort* base = H1 + (size_t)(t0 + row) * 11 * 128;
    const ushort2 s = *(const ushort2*)(base + lane * 2);
    float ax = 0.f, ay = 0.f;
#pragma unroll
    for (int j = 1; j <= 10; ++j) {
      const ushort2 v = *(const ushort2*)(base + j * 128 + lane * 2);
      ax += bf2f(v.x); ay += bf2f(v.y);
    }
    *(ushort2*)(Xs + row * 264 + lane * 2) = s;
    ushort2 m;
    m.x = f2bf(ax * 0.1f); m.y = f2bf(ay * 0.1f);
    *(ushort2*)(Xs + row * 264 + 128 + lane * 2) = m;
  }
  __syncthreads();
  gemm_norm_64<0>(Xs, Wt, ssb, Wb1, b1, (void*)out, t0);
}

extern "C" void kernel_launch(void* const* d_in, const int* in_sizes, int n_in,
                              void* d_out, int out_size, void* d_ws, size_t ws_size,
                              hipStream_t stream) {
  const float* feat  = (const float*)d_in[0];   // [1e6,128]
  const float* W0    = (const float*)d_in[1];   // [128,256]
  const float* b0    = (const float*)d_in[2];   // [128]
  const float* W1    = (const float*)d_in[3];   // [128,256]
  const float* b1    = (const float*)d_in[4];   // [128]
  const int* nodes   = (const int*)d_in[5];     // [4096]
  const int* nbr1    = (const int*)d_in[6];     // [4096,10]
  const int* nbr0    = (const int*)d_in[7];     // [4096,11,25]
  float* out = (float*)d_out;                   // [4096,128] f32

  // workspace layout (16B aligned)
  ushort* Wb0 = (ushort*)d_ws;                              // 65,536 B
  ushort* Wb1 = (ushort*)((char*)d_ws + 65536);             // 65,536 B
  ushort* H1  = (ushort*)((char*)d_ws + 131072);            // 45056*128*2 = 11,534,336 B

  // P: W0,W1 -> bf16 once
  prep_w_kernel<<<64, 256, 0, stream>>>(W0, W1, Wb0, Wb1);
  // L1 fused: gather+mean -> GEMM -> H1 bf16 [45056,128]
  fused_l1_kernel<<<L1N / 64, 512, 0, stream>>>(feat, nodes, nbr1, nbr0, Wb0, b0, H1);
  // L2 fused: X2 build -> GEMM -> z f32 [4096,128]
  fused_l2_kernel<<<NBATCH / 64, 512, 0, stream>>>(H1, Wb1, b1, out);
}